// Round 1
// baseline (395.989 us; speedup 1.0000x reference)
//
#include <hip/hip_runtime.h>
#include <hip/hip_bf16.h>

#define FDIM 256
#define NATOMS 64

using bf16x8 = __attribute__((ext_vector_type(8))) short;
using f32x4  = __attribute__((ext_vector_type(4))) float;

__device__ __forceinline__ float sigm(float x) { return 1.0f / (1.0f + __expf(-x)); }

// ---------------- prep 1: wk± = W_lin @ k±, bk± = b_lin . k± ----------------
__global__ void prep_wk(const float* __restrict__ W_lin, const float* __restrict__ b_lin,
                        const float* __restrict__ kp, const float* __restrict__ km,
                        float* __restrict__ wkp, float* __restrict__ wkm,
                        float* __restrict__ bk2) {
    const int f = blockIdx.x;   // output row of W_lin @ k
    const int t = threadIdx.x;  // reduction index
    __shared__ float sp[FDIM], sm[FDIM];
    float w = W_lin[(size_t)f * FDIM + t];
    sp[t] = w * kp[t];
    sm[t] = w * km[t];
    __syncthreads();
    for (int s = 128; s > 0; s >>= 1) {
        if (t < s) { sp[t] += sp[t + s]; sm[t] += sm[t + s]; }
        __syncthreads();
    }
    if (t == 0) { wkp[f] = sp[0]; wkm[f] = sm[0]; }
    if (f == 0) {
        __syncthreads();
        sp[t] = b_lin[t] * kp[t];
        sm[t] = b_lin[t] * km[t];
        __syncthreads();
        for (int s = 128; s > 0; s >>= 1) {
            if (t < s) { sp[t] += sp[t + s]; sm[t] += sm[t + s]; }
            __syncthreads();
        }
        if (t == 0) { bk2[0] = sp[0]; bk2[1] = sm[0]; }
    }
}

// ---------------- prep 2: Wt[n][k] = bf16(W[k][n]) for the 3 MLP weights ----------------
__global__ void prep_wt(const float* __restrict__ W1, const float* __restrict__ W2,
                        const float* __restrict__ W3,
                        __hip_bfloat16* __restrict__ Wt1, __hip_bfloat16* __restrict__ Wt2,
                        __hip_bfloat16* __restrict__ Wt3) {
    const int b = blockIdx.x;
    const int mat = b >> 8;
    const int n = b & 255;
    const int k = threadIdx.x;
    const float* W = (mat == 0) ? W1 : (mat == 1) ? W2 : W3;
    __hip_bfloat16* Wt = (mat == 0) ? Wt1 : (mat == 1) ? Wt2 : Wt3;
    Wt[(size_t)n * FDIM + k] = __float2bfloat16(W[(size_t)k * FDIM + n]);
}

// ---------------- fused: attention scalar a_i + 3-GEMM residual MLP ----------------
__global__ __launch_bounds__(256) void fused_ee(
    const float* __restrict__ psi, const float* __restrict__ e_z,
    const float* __restrict__ wkp, const float* __restrict__ wkm,
    const float* __restrict__ bk2,
    const float* __restrict__ vp, const float* __restrict__ vm,
    const __hip_bfloat16* __restrict__ Wt1, const __hip_bfloat16* __restrict__ Wt2,
    const __hip_bfloat16* __restrict__ Wt3,
    const float* __restrict__ a1, const float* __restrict__ be1,
    const float* __restrict__ a2, const float* __restrict__ be2,
    const float* __restrict__ a3, const float* __restrict__ be3,
    const float* __restrict__ b_out, float* __restrict__ out) {

    constexpr int LDX = FDIM + 8;  // +16B pad per row: fragment ds_read_b128 at 2 lanes/bank
    __shared__ __hip_bfloat16 X[NATOMS][LDX];
    __shared__ float nums[NATOMS];
    __shared__ float aL[NATOMS];
    __shared__ float denomS;

    const int tid = threadIdx.x;
    const int lane = tid & 63;
    const int wv = tid >> 6;
    const int mol = blockIdx.x;
    const float psiv = psi[mol];
    const bool pos = (psiv >= 0.0f);

    // ---- attention: arg_i = (e_z[i].wk + bk)/16 ; num = softplus(arg) ----
    {
        const float* wk = pos ? wkp : wkm;
        const float bk = pos ? bk2[0] : bk2[1];
        const float4 wkv = reinterpret_cast<const float4*>(wk)[lane];
        for (int a = wv; a < NATOMS; a += 4) {
            const float4 ev =
                reinterpret_cast<const float4*>(e_z + ((size_t)mol * NATOMS + a) * FDIM)[lane];
            float d = ev.x * wkv.x + ev.y * wkv.y + ev.z * wkv.z + ev.w * wkv.w;
#pragma unroll
            for (int off = 32; off > 0; off >>= 1) d += __shfl_xor(d, off, 64);
            if (lane == 0) {
                float arg = (d + bk) * 0.0625f;
                nums[a] = fmaxf(arg, 0.0f) + log1pf(__expf(-fabsf(arg)));
            }
        }
    }
    __syncthreads();
    if (tid < 64) {
        float s = nums[tid];
#pragma unroll
        for (int off = 32; off > 0; off >>= 1) s += __shfl_xor(s, off, 64);
        if (tid == 0) denomS = s;
    }
    __syncthreads();
    if (tid < 64) aL[tid] = psiv * nums[tid] / denomS;
    __syncthreads();

    // ---- stage-1 input: X = bf16(swish1(a_i * v)) ----
    {
        const int c = tid;
        const float vc = pos ? vp[c] : vm[c];
        const float a1c = a1[c], be1c = be1[c];
#pragma unroll 4
        for (int r = 0; r < NATOMS; ++r) {
            float x0 = aL[r] * vc;
            X[r][c] = __float2bfloat16(a1c * x0 * sigm(be1c * x0));
        }
    }

    // per-wave column params (wave owns cols wv*64 .. wv*64+63)
    int cw[4];
    float a2v[4], be2v[4], a3v[4], be3v[4], vv[4], bbv[4];
#pragma unroll
    for (int n = 0; n < 4; ++n) {
        int cc = wv * 64 + n * 16 + (lane & 15);
        cw[n] = cc;
        a2v[n] = a2[cc]; be2v[n] = be2[cc];
        a3v[n] = a3[cc]; be3v[n] = be3[cc];
        vv[n] = pos ? vp[cc] : vm[cc];
        bbv[n] = b_out[cc];
    }

    __syncthreads();

    f32x4 acc[4][4];
    const int arow = lane & 15;
    const int kg = (lane >> 4) * 8;
    const f32x4 zero = {0.f, 0.f, 0.f, 0.f};

    auto run_gemm = [&](const __hip_bfloat16* __restrict__ Wt) {
#pragma unroll
        for (int m = 0; m < 4; ++m)
#pragma unroll
            for (int n = 0; n < 4; ++n) acc[m][n] = zero;
#pragma unroll 2
        for (int k0 = 0; k0 < FDIM; k0 += 32) {
            bf16x8 af[4], bfr[4];
#pragma unroll
            for (int m = 0; m < 4; ++m)
                af[m] = *reinterpret_cast<const bf16x8*>(&X[m * 16 + arow][k0 + kg]);
#pragma unroll
            for (int n = 0; n < 4; ++n)
                bfr[n] = *reinterpret_cast<const bf16x8*>(&Wt[(size_t)cw[n] * FDIM + k0 + kg]);
#pragma unroll
            for (int m = 0; m < 4; ++m)
#pragma unroll
                for (int n = 0; n < 4; ++n)
                    acc[m][n] =
                        __builtin_amdgcn_mfma_f32_16x16x32_bf16(af[m], bfr[n], acc[m][n], 0, 0, 0);
        }
    };

    // ---- stage 1: y1 = X @ W_r1 ; X = bf16(swish2(y1)) ----
    run_gemm(Wt1);
    __syncthreads();
#pragma unroll
    for (int m = 0; m < 4; ++m)
#pragma unroll
        for (int n = 0; n < 4; ++n)
#pragma unroll
            for (int j = 0; j < 4; ++j) {
                int row = m * 16 + (lane >> 4) * 4 + j;
                float y = acc[m][n][j];
                X[row][cw[n]] = __float2bfloat16(a2v[n] * y * sigm(be2v[n] * y));
            }
    __syncthreads();

    // ---- stage 2: y2 = X @ W_r2 ; h = av + y2 ; X = bf16(swish3(h)) ----
    run_gemm(Wt2);
    __syncthreads();
#pragma unroll
    for (int m = 0; m < 4; ++m)
#pragma unroll
        for (int n = 0; n < 4; ++n)
#pragma unroll
            for (int j = 0; j < 4; ++j) {
                int row = m * 16 + (lane >> 4) * 4 + j;
                float h = aL[row] * vv[n] + acc[m][n][j];
                X[row][cw[n]] = __float2bfloat16(a3v[n] * h * sigm(be3v[n] * h));
            }
    __syncthreads();

    // ---- stage 3: out = X @ W_out + b_out ----
    run_gemm(Wt3);
#pragma unroll
    for (int m = 0; m < 4; ++m)
#pragma unroll
        for (int n = 0; n < 4; ++n)
#pragma unroll
            for (int j = 0; j < 4; ++j) {
                int row = m * 16 + (lane >> 4) * 4 + j;
                out[((size_t)mol * NATOMS + row) * FDIM + cw[n]] = acc[m][n][j] + bbv[n];
            }
}

extern "C" void kernel_launch(void* const* d_in, const int* in_sizes, int n_in,
                              void* d_out, int out_size, void* d_ws, size_t ws_size,
                              hipStream_t stream) {
    const float* psi     = (const float*)d_in[0];
    const float* e_z     = (const float*)d_in[1];
    // d_in[2] = num_atoms (uniformly 64; mol_idx = atom/64)
    const float* W_lin   = (const float*)d_in[3];
    const float* b_lin   = (const float*)d_in[4];
    const float* k_plus  = (const float*)d_in[5];
    const float* k_minus = (const float*)d_in[6];
    const float* v_plus  = (const float*)d_in[7];
    const float* v_minus = (const float*)d_in[8];
    const float* W_r1    = (const float*)d_in[9];
    const float* W_r2    = (const float*)d_in[10];
    const float* W_out   = (const float*)d_in[11];
    const float* b_out   = (const float*)d_in[12];
    const float* a1      = (const float*)d_in[13];
    const float* be1     = (const float*)d_in[14];
    const float* a2      = (const float*)d_in[15];
    const float* be2     = (const float*)d_in[16];
    const float* a3      = (const float*)d_in[17];
    const float* be3     = (const float*)d_in[18];
    float* out = (float*)d_out;

    char* ws = (char*)d_ws;
    float* wkp = (float*)ws;                 // 256 f32
    float* wkm = wkp + FDIM;                 // 256 f32
    float* bk2 = wkm + FDIM;                 // 2 f32
    __hip_bfloat16* Wt1 = (__hip_bfloat16*)(ws + 4096);
    __hip_bfloat16* Wt2 = Wt1 + FDIM * FDIM;
    __hip_bfloat16* Wt3 = Wt2 + FDIM * FDIM;

    const int n_mol = in_sizes[0];

    prep_wk<<<FDIM, FDIM, 0, stream>>>(W_lin, b_lin, k_plus, k_minus, wkp, wkm, bk2);
    prep_wt<<<3 * FDIM, FDIM, 0, stream>>>(W_r1, W_r2, W_out, Wt1, Wt2, Wt3);
    fused_ee<<<n_mol, 256, 0, stream>>>(psi, e_z, wkp, wkm, bk2, v_plus, v_minus,
                                        Wt1, Wt2, Wt3, a1, be1, a2, be2, a3, be3,
                                        b_out, out);
}

// Round 2
// 313.431 us; speedup vs baseline: 1.2634x; 1.2634x over previous
//
#include <hip/hip_runtime.h>
#include <hip/hip_bf16.h>

#define FDIM 256
#define NATOMS 64
#define LDX 264  // row stride: 528B = 132 dwords ≡ 4 (mod 32) → uniform bank spread for b128

using bf16x8 = __attribute__((ext_vector_type(8))) short;
using f32x4  = __attribute__((ext_vector_type(4))) float;

__device__ __forceinline__ float fast_sigm(float x) {
    // 1 v_exp + 1 v_add + 1 v_rcp instead of the ~10-inst IEEE div sequence
    return __builtin_amdgcn_rcpf(1.0f + __expf(-x));
}
__device__ __forceinline__ unsigned cvt_pk_bf16(float lo, float hi) {
    unsigned r;
    asm("v_cvt_pk_bf16_f32 %0, %1, %2" : "=v"(r) : "v"(lo), "v"(hi));
    return r;  // D[15:0]=bf16(lo), D[31:16]=bf16(hi)
}

// ---------------- prep 1: wk± = W_lin @ k±, bk± = b_lin . k± ----------------
__global__ void prep_wk(const float* __restrict__ W_lin, const float* __restrict__ b_lin,
                        const float* __restrict__ kp, const float* __restrict__ km,
                        float* __restrict__ wkp, float* __restrict__ wkm,
                        float* __restrict__ bk2) {
    const int f = blockIdx.x;
    const int t = threadIdx.x;
    __shared__ float sp[FDIM], sm[FDIM];
    float w = W_lin[(size_t)f * FDIM + t];
    sp[t] = w * kp[t];
    sm[t] = w * km[t];
    __syncthreads();
    for (int s = 128; s > 0; s >>= 1) {
        if (t < s) { sp[t] += sp[t + s]; sm[t] += sm[t + s]; }
        __syncthreads();
    }
    if (t == 0) { wkp[f] = sp[0]; wkm[f] = sm[0]; }
    if (f == 0) {
        __syncthreads();
        sp[t] = b_lin[t] * kp[t];
        sm[t] = b_lin[t] * km[t];
        __syncthreads();
        for (int s = 128; s > 0; s >>= 1) {
            if (t < s) { sp[t] += sp[t + s]; sm[t] += sm[t + s]; }
            __syncthreads();
        }
        if (t == 0) { bk2[0] = sp[0]; bk2[1] = sm[0]; }
    }
}

// ---------------- prep 2: Wt[n][k] = bf16(W[k][n]) for the 3 MLP weights ----------------
__global__ void prep_wt(const float* __restrict__ W1, const float* __restrict__ W2,
                        const float* __restrict__ W3,
                        __hip_bfloat16* __restrict__ Wt1, __hip_bfloat16* __restrict__ Wt2,
                        __hip_bfloat16* __restrict__ Wt3) {
    const int b = blockIdx.x;
    const int mat = b >> 8;
    const int n = b & 255;
    const int k = threadIdx.x;
    const float* W = (mat == 0) ? W1 : (mat == 1) ? W2 : W3;
    __hip_bfloat16* Wt = (mat == 0) ? Wt1 : (mat == 1) ? Wt2 : Wt3;
    Wt[(size_t)n * FDIM + k] = __float2bfloat16(W[(size_t)k * FDIM + n]);
}

// ---------------- fused: attention scalar a_i + 3-GEMM residual MLP ----------------
// Transposed-GEMM formulation: D[feat][atom] = mfma(A=Wt_rowfrag, B=Xrow_frag).
// C-fragment per lane = 4 CONSECUTIVE features, one atom -> packed bf16 epilogues.
__global__ __launch_bounds__(256) void fused_ee(
    const float* __restrict__ psi, const float* __restrict__ e_z,
    const float* __restrict__ wkp, const float* __restrict__ wkm,
    const float* __restrict__ bk2,
    const float* __restrict__ vp, const float* __restrict__ vm,
    const __hip_bfloat16* __restrict__ Wt1, const __hip_bfloat16* __restrict__ Wt2,
    const __hip_bfloat16* __restrict__ Wt3,
    const float* __restrict__ a1g, const float* __restrict__ be1g,
    const float* __restrict__ a2g, const float* __restrict__ be2g,
    const float* __restrict__ a3g, const float* __restrict__ be3g,
    const float* __restrict__ b_out, float* __restrict__ out) {

    __shared__ __hip_bfloat16 X[NATOMS][LDX];
    __shared__ float nums[NATOMS];
    __shared__ float aLs[NATOMS];
    __shared__ float vselS[FDIM], a2s[FDIM], be2s[FDIM], a3s[FDIM], be3s[FDIM], bbs[FDIM];

    const int tid = threadIdx.x;
    const int lane = tid & 63;
    const int wv = tid >> 6;
    const int l15 = lane & 15;
    const int hi4 = lane >> 4;  // 0..3
    const int mol = blockIdx.x;
    const float psiv = psi[mol];
    const bool pos = (psiv >= 0.0f);

    // stage per-feature params into LDS (one element per thread)
    vselS[tid] = pos ? vp[tid] : vm[tid];
    a2s[tid] = a2g[tid]; be2s[tid] = be2g[tid];
    a3s[tid] = a3g[tid]; be3s[tid] = be3g[tid];
    bbs[tid] = b_out[tid];

    // ---- attention dots: raw arg into nums ----
    {
        const float* wk = pos ? wkp : wkm;
        const float bk = pos ? bk2[0] : bk2[1];
        const float4 wkv = reinterpret_cast<const float4*>(wk)[lane];
        for (int a = wv; a < NATOMS; a += 4) {
            const float4 ev =
                reinterpret_cast<const float4*>(e_z + ((size_t)mol * NATOMS + a) * FDIM)[lane];
            float d = ev.x * wkv.x + ev.y * wkv.y + ev.z * wkv.z + ev.w * wkv.w;
#pragma unroll
            for (int off = 32; off > 0; off >>= 1) d += __shfl_xor(d, off, 64);
            if (lane == 0) nums[a] = (d + bk) * 0.0625f;
        }
    }
    __syncthreads();
    // ---- wave 0: softplus (64-lane parallel), denom reduce, a_i ----
    if (tid < 64) {
        float arg = nums[tid];
        float nv = fmaxf(arg, 0.0f) + log1pf(__expf(-fabsf(arg)));
        float s = nv;
#pragma unroll
        for (int off = 32; off > 0; off >>= 1) s += __shfl_xor(s, off, 64);
        aLs[tid] = psiv * nv * __builtin_amdgcn_rcpf(s);
    }
    __syncthreads();

    // ---- stage-1 input: X[r][c] = bf16(swish1(a_r * v_c)), packed 4-wide ----
    {
        const int c0 = (tid & 63) * 4;
        const int r0 = wv * 16;
        const float4 v4  = *reinterpret_cast<const float4*>(&vselS[c0]);
        const float4 a14 = *reinterpret_cast<const float4*>(&a1g[c0]);
        const float4 b14 = *reinterpret_cast<const float4*>(&be1g[c0]);
#pragma unroll 4
        for (int i = 0; i < 16; ++i) {
            const float al = aLs[r0 + i];
            float x0 = al * v4.x, x1 = al * v4.y, x2 = al * v4.z, x3 = al * v4.w;
            float s0 = a14.x * x0 * fast_sigm(b14.x * x0);
            float s1 = a14.y * x1 * fast_sigm(b14.y * x1);
            float s2 = a14.z * x2 * fast_sigm(b14.z * x2);
            float s3 = a14.w * x3 * fast_sigm(b14.w * x3);
            uint2 pk;
            pk.x = cvt_pk_bf16(s0, s1);
            pk.y = cvt_pk_bf16(s2, s3);
            *reinterpret_cast<uint2*>(&X[r0 + i][c0]) = pk;
        }
    }
    __syncthreads();

    // ---- GEMM machinery (transposed): wave owns feats [wv*64, wv*64+64), all 64 atoms ----
    const int fbase = wv * 64 + l15;       // A-frag feature row
    const int kg = hi4 * 8;                // k sub-offset within 32-wide k-step
    const int f0 = wv * 64 + hi4 * 4;      // C-frag feature base (+ m*16)
    const __hip_bfloat16* xbase = &X[l15][kg];

    f32x4 acc[4][4];
    const f32x4 zero = {0.f, 0.f, 0.f, 0.f};

    auto run_gemm = [&](const __hip_bfloat16* __restrict__ Wt) {
        const __hip_bfloat16* wrow[4];
#pragma unroll
        for (int m = 0; m < 4; ++m) wrow[m] = Wt + (size_t)(fbase + m * 16) * FDIM + kg;
#pragma unroll
        for (int m = 0; m < 4; ++m)
#pragma unroll
            for (int n = 0; n < 4; ++n) acc[m][n] = zero;
#pragma unroll
        for (int k0 = 0; k0 < FDIM; k0 += 32) {
            bf16x8 af[4], bfr[4];
#pragma unroll
            for (int m = 0; m < 4; ++m)
                af[m] = *reinterpret_cast<const bf16x8*>(wrow[m] + k0);
#pragma unroll
            for (int n = 0; n < 4; ++n)
                bfr[n] = *reinterpret_cast<const bf16x8*>(xbase + n * (16 * LDX) + k0);
#pragma unroll
            for (int m = 0; m < 4; ++m)
#pragma unroll
                for (int n = 0; n < 4; ++n)
                    acc[m][n] =
                        __builtin_amdgcn_mfma_f32_16x16x32_bf16(af[m], bfr[n], acc[m][n], 0, 0, 0);
        }
    };

    // ---- stage 1: y1^T = Wt1 . X^T ; X = bf16(swish2(y1)) ----
    run_gemm(Wt1);
    __syncthreads();
#pragma unroll
    for (int m = 0; m < 4; ++m) {
        const int fm = f0 + m * 16;
        const float4 av4 = *reinterpret_cast<const float4*>(&a2s[fm]);
        const float4 bv4 = *reinterpret_cast<const float4*>(&be2s[fm]);
#pragma unroll
        for (int n = 0; n < 4; ++n) {
            f32x4 y = acc[m][n];
            float s0 = av4.x * y[0] * fast_sigm(bv4.x * y[0]);
            float s1 = av4.y * y[1] * fast_sigm(bv4.y * y[1]);
            float s2 = av4.z * y[2] * fast_sigm(bv4.z * y[2]);
            float s3 = av4.w * y[3] * fast_sigm(bv4.w * y[3]);
            uint2 pk;
            pk.x = cvt_pk_bf16(s0, s1);
            pk.y = cvt_pk_bf16(s2, s3);
            *reinterpret_cast<uint2*>(&X[n * 16 + l15][fm]) = pk;
        }
    }
    __syncthreads();

    // ---- stage 2: y2^T = Wt2 . X^T ; h = av + y2 ; X = bf16(swish3(h)) ----
    run_gemm(Wt2);
    __syncthreads();
    {
        float aln[4];
#pragma unroll
        for (int n = 0; n < 4; ++n) aln[n] = aLs[n * 16 + l15];
#pragma unroll
        for (int m = 0; m < 4; ++m) {
            const int fm = f0 + m * 16;
            const float4 av4 = *reinterpret_cast<const float4*>(&a3s[fm]);
            const float4 bv4 = *reinterpret_cast<const float4*>(&be3s[fm]);
            const float4 vv4 = *reinterpret_cast<const float4*>(&vselS[fm]);
#pragma unroll
            for (int n = 0; n < 4; ++n) {
                f32x4 y = acc[m][n];
                float h0 = fmaf(aln[n], vv4.x, y[0]);
                float h1 = fmaf(aln[n], vv4.y, y[1]);
                float h2 = fmaf(aln[n], vv4.z, y[2]);
                float h3 = fmaf(aln[n], vv4.w, y[3]);
                float s0 = av4.x * h0 * fast_sigm(bv4.x * h0);
                float s1 = av4.y * h1 * fast_sigm(bv4.y * h1);
                float s2 = av4.z * h2 * fast_sigm(bv4.z * h2);
                float s3 = av4.w * h3 * fast_sigm(bv4.w * h3);
                uint2 pk;
                pk.x = cvt_pk_bf16(s0, s1);
                pk.y = cvt_pk_bf16(s2, s3);
                *reinterpret_cast<uint2*>(&X[n * 16 + l15][fm]) = pk;
            }
        }
    }
    __syncthreads();

    // ---- stage 3: out^T = Wt3 . X^T + b_out ; coalesced-ish dwordx4 stores ----
    run_gemm(Wt3);
    float* obase = out + ((size_t)mol * NATOMS + l15) * FDIM + f0;
#pragma unroll
    for (int m = 0; m < 4; ++m) {
        const float4 bb4 = *reinterpret_cast<const float4*>(&bbs[f0 + m * 16]);
#pragma unroll
        for (int n = 0; n < 4; ++n) {
            float4 r;
            r.x = acc[m][n][0] + bb4.x;
            r.y = acc[m][n][1] + bb4.y;
            r.z = acc[m][n][2] + bb4.z;
            r.w = acc[m][n][3] + bb4.w;
            *reinterpret_cast<float4*>(obase + (size_t)n * 16 * FDIM + m * 16) = r;
        }
    }
}

extern "C" void kernel_launch(void* const* d_in, const int* in_sizes, int n_in,
                              void* d_out, int out_size, void* d_ws, size_t ws_size,
                              hipStream_t stream) {
    const float* psi     = (const float*)d_in[0];
    const float* e_z     = (const float*)d_in[1];
    // d_in[2] = num_atoms (uniformly 64; mol_idx = atom/64)
    const float* W_lin   = (const float*)d_in[3];
    const float* b_lin   = (const float*)d_in[4];
    const float* k_plus  = (const float*)d_in[5];
    const float* k_minus = (const float*)d_in[6];
    const float* v_plus  = (const float*)d_in[7];
    const float* v_minus = (const float*)d_in[8];
    const float* W_r1    = (const float*)d_in[9];
    const float* W_r2    = (const float*)d_in[10];
    const float* W_out   = (const float*)d_in[11];
    const float* b_out   = (const float*)d_in[12];
    const float* a1      = (const float*)d_in[13];
    const float* be1     = (const float*)d_in[14];
    const float* a2      = (const float*)d_in[15];
    const float* be2     = (const float*)d_in[16];
    const float* a3      = (const float*)d_in[17];
    const float* be3     = (const float*)d_in[18];
    float* out = (float*)d_out;

    char* ws = (char*)d_ws;
    float* wkp = (float*)ws;                 // 256 f32
    float* wkm = wkp + FDIM;                 // 256 f32
    float* bk2 = wkm + FDIM;                 // 2 f32
    __hip_bfloat16* Wt1 = (__hip_bfloat16*)(ws + 4096);
    __hip_bfloat16* Wt2 = Wt1 + FDIM * FDIM;
    __hip_bfloat16* Wt3 = Wt2 + FDIM * FDIM;

    const int n_mol = in_sizes[0];

    prep_wk<<<FDIM, FDIM, 0, stream>>>(W_lin, b_lin, k_plus, k_minus, wkp, wkm, bk2);
    prep_wt<<<3 * FDIM, FDIM, 0, stream>>>(W_r1, W_r2, W_out, Wt1, Wt2, Wt3);
    fused_ee<<<n_mol, 256, 0, stream>>>(psi, e_z, wkp, wkm, bk2, v_plus, v_minus,
                                        Wt1, Wt2, Wt3, a1, be1, a2, be2, a3, be3,
                                        b_out, out);
}

// Round 3
// 312.200 us; speedup vs baseline: 1.2684x; 1.0039x over previous
//
#include <hip/hip_runtime.h>
#include <hip/hip_bf16.h>

#define FDIM 256
#define NATOMS 64
#define LDX 264  // row stride 528B = 132 dwords ≡ 4 (mod 32): +1 bank-quad shift per row

using bf16x8 = __attribute__((ext_vector_type(8))) short;
using f32x4  = __attribute__((ext_vector_type(4))) float;

__device__ __forceinline__ float fast_sigm(float x) {
    return __builtin_amdgcn_rcpf(1.0f + __expf(-x));
}
__device__ __forceinline__ unsigned cvt_pk_bf16(float lo, float hi) {
    unsigned r;
    asm("v_cvt_pk_bf16_f32 %0, %1, %2" : "=v"(r) : "v"(lo), "v"(hi));
    return r;
}

// ---------------- prep 1: wk± = W_lin @ k±, bk± = b_lin . k± ----------------
__global__ void prep_wk(const float* __restrict__ W_lin, const float* __restrict__ b_lin,
                        const float* __restrict__ kp, const float* __restrict__ km,
                        float* __restrict__ wkp, float* __restrict__ wkm,
                        float* __restrict__ bk2) {
    const int f = blockIdx.x;
    const int t = threadIdx.x;
    __shared__ float sp[FDIM], sm[FDIM];
    float w = W_lin[(size_t)f * FDIM + t];
    sp[t] = w * kp[t];
    sm[t] = w * km[t];
    __syncthreads();
    for (int s = 128; s > 0; s >>= 1) {
        if (t < s) { sp[t] += sp[t + s]; sm[t] += sm[t + s]; }
        __syncthreads();
    }
    if (t == 0) { wkp[f] = sp[0]; wkm[f] = sm[0]; }
    if (f == 0) {
        __syncthreads();
        sp[t] = b_lin[t] * kp[t];
        sm[t] = b_lin[t] * km[t];
        __syncthreads();
        for (int s = 128; s > 0; s >>= 1) {
            if (t < s) { sp[t] += sp[t + s]; sm[t] += sm[t + s]; }
            __syncthreads();
        }
        if (t == 0) { bk2[0] = sp[0]; bk2[1] = sm[0]; }
    }
}

// ---------------- prep 2: Wt[n][k] = bf16(W[k][n]) ----------------
__global__ void prep_wt(const float* __restrict__ W1, const float* __restrict__ W2,
                        const float* __restrict__ W3,
                        __hip_bfloat16* __restrict__ Wt1, __hip_bfloat16* __restrict__ Wt2,
                        __hip_bfloat16* __restrict__ Wt3) {
    const int b = blockIdx.x;
    const int mat = b >> 8;
    const int n = b & 255;
    const int k = threadIdx.x;
    const float* W = (mat == 0) ? W1 : (mat == 1) ? W2 : W3;
    __hip_bfloat16* Wt = (mat == 0) ? Wt1 : (mat == 1) ? Wt2 : Wt3;
    Wt[(size_t)n * FDIM + k] = __float2bfloat16(W[(size_t)k * FDIM + n]);
}

// ---------------- fused: attention scalar a_i + 3-GEMM residual MLP ----------------
// 8 waves / molecule. Wave wv owns features [wv*32, wv*32+32) x all 64 atoms.
__global__ __launch_bounds__(512, 6) void fused_ee(
    const float* __restrict__ psi, const float* __restrict__ e_z,
    const float* __restrict__ wkp, const float* __restrict__ wkm,
    const float* __restrict__ bk2,
    const float* __restrict__ vp, const float* __restrict__ vm,
    const __hip_bfloat16* __restrict__ Wt1, const __hip_bfloat16* __restrict__ Wt2,
    const __hip_bfloat16* __restrict__ Wt3,
    const float* __restrict__ a1g, const float* __restrict__ be1g,
    const float* __restrict__ a2g, const float* __restrict__ be2g,
    const float* __restrict__ a3g, const float* __restrict__ be3g,
    const float* __restrict__ b_out, float* __restrict__ out) {

    __shared__ __hip_bfloat16 X[NATOMS][LDX];
    __shared__ float nums[NATOMS];
    __shared__ float aLs[NATOMS];

    const int tid = threadIdx.x;
    const int lane = tid & 63;
    const int wv = tid >> 6;       // 0..7
    const int l15 = lane & 15;
    const int hi4 = lane >> 4;     // 0..3
    const int mol = blockIdx.x;
    const float psiv = psi[mol];
    const bool pos = (psiv >= 0.0f);

    // ---- attention dots: batch-issue all 8 e_z row loads, then reduce ----
    {
        const float* wk = pos ? wkp : wkm;
        const float bk = pos ? bk2[0] : bk2[1];
        const float4 wkv = reinterpret_cast<const float4*>(wk)[lane];
        const float4* ez4 = reinterpret_cast<const float4*>(e_z + (size_t)mol * NATOMS * FDIM);
        float4 ev[8];
#pragma unroll
        for (int i = 0; i < 8; ++i) ev[i] = ez4[(size_t)(wv * 8 + i) * 64 + lane];
#pragma unroll
        for (int i = 0; i < 8; ++i) {
            float d = ev[i].x * wkv.x + ev[i].y * wkv.y + ev[i].z * wkv.z + ev[i].w * wkv.w;
#pragma unroll
            for (int off = 32; off > 0; off >>= 1) d += __shfl_xor(d, off, 64);
            if (lane == 0) nums[wv * 8 + i] = (d + bk) * 0.0625f;
        }
    }
    __syncthreads();
    // ---- wave 0: softplus (64-lane), denom reduce, a_i ----
    if (tid < 64) {
        float arg = nums[tid];
        float nv = fmaxf(arg, 0.0f) + log1pf(__expf(-fabsf(arg)));
        float s = nv;
#pragma unroll
        for (int off = 32; off > 0; off >>= 1) s += __shfl_xor(s, off, 64);
        aLs[tid] = psiv * nv * __builtin_amdgcn_rcpf(s);
    }
    __syncthreads();

    // ---- stage-1 input: X[r][c] = bf16(swish1(a_r * v_c)), rows wv*8..+8 ----
    {
        const int c0 = lane * 4;
        const int r0 = wv * 8;
        const float4 v4  = pos ? reinterpret_cast<const float4*>(vp)[lane]
                               : reinterpret_cast<const float4*>(vm)[lane];
        const float4 a14 = reinterpret_cast<const float4*>(a1g)[lane];
        const float4 b14 = reinterpret_cast<const float4*>(be1g)[lane];
#pragma unroll
        for (int i = 0; i < 8; ++i) {
            const float al = aLs[r0 + i];
            float x0 = al * v4.x, x1 = al * v4.y, x2 = al * v4.z, x3 = al * v4.w;
            float s0 = a14.x * x0 * fast_sigm(b14.x * x0);
            float s1 = a14.y * x1 * fast_sigm(b14.y * x1);
            float s2 = a14.z * x2 * fast_sigm(b14.z * x2);
            float s3 = a14.w * x3 * fast_sigm(b14.w * x3);
            uint2 pk;
            pk.x = cvt_pk_bf16(s0, s1);
            pk.y = cvt_pk_bf16(s2, s3);
            *reinterpret_cast<uint2*>(&X[r0 + i][c0]) = pk;
        }
    }

    // ---- GEMM machinery: A = Wt rows (global/L2), B = X rows (LDS) ----
    const int fbase = wv * 32 + l15;   // A-frag feature row (+ m*16)
    const int kg = hi4 * 8;            // k sub-offset
    const int f0 = wv * 32 + hi4 * 4;  // C-frag feature base (+ m*16)
    const __hip_bfloat16* xbase = &X[l15][kg];

    f32x4 acc[2][4];
    const f32x4 zero = {0.f, 0.f, 0.f, 0.f};

    auto run_gemm = [&](const __hip_bfloat16* __restrict__ Wt) {
        const __hip_bfloat16* wrow0 = Wt + (size_t)fbase * FDIM + kg;
        const __hip_bfloat16* wrow1 = wrow0 + 16 * FDIM;
#pragma unroll
        for (int m = 0; m < 2; ++m)
#pragma unroll
            for (int n = 0; n < 4; ++n) acc[m][n] = zero;
#pragma unroll
        for (int k0 = 0; k0 < FDIM; k0 += 32) {
            bf16x8 af[2], bfr[4];
            af[0] = *reinterpret_cast<const bf16x8*>(wrow0 + k0);
            af[1] = *reinterpret_cast<const bf16x8*>(wrow1 + k0);
#pragma unroll
            for (int n = 0; n < 4; ++n)
                bfr[n] = *reinterpret_cast<const bf16x8*>(xbase + n * (16 * LDX) + k0);
#pragma unroll
            for (int m = 0; m < 2; ++m)
#pragma unroll
                for (int n = 0; n < 4; ++n)
                    acc[m][n] =
                        __builtin_amdgcn_mfma_f32_16x16x32_bf16(af[m], bfr[n], acc[m][n], 0, 0, 0);
        }
    };

    // ---- stage 1: y1^T = Wt1 . X^T ; X = bf16(swish2(y1)) ----
    // prefetch epilogue-1 params while GEMM runs
    float4 pa[2], pb[2];
#pragma unroll
    for (int m = 0; m < 2; ++m) {
        pa[m] = *reinterpret_cast<const float4*>(a2g + f0 + m * 16);
        pb[m] = *reinterpret_cast<const float4*>(be2g + f0 + m * 16);
    }
    __syncthreads();
    run_gemm(Wt1);
    __syncthreads();
#pragma unroll
    for (int m = 0; m < 2; ++m) {
        const int fm = f0 + m * 16;
#pragma unroll
        for (int n = 0; n < 4; ++n) {
            f32x4 y = acc[m][n];
            float s0 = pa[m].x * y[0] * fast_sigm(pb[m].x * y[0]);
            float s1 = pa[m].y * y[1] * fast_sigm(pb[m].y * y[1]);
            float s2 = pa[m].z * y[2] * fast_sigm(pb[m].z * y[2]);
            float s3 = pa[m].w * y[3] * fast_sigm(pb[m].w * y[3]);
            uint2 pk;
            pk.x = cvt_pk_bf16(s0, s1);
            pk.y = cvt_pk_bf16(s2, s3);
            *reinterpret_cast<uint2*>(&X[n * 16 + l15][fm]) = pk;
        }
    }

    // ---- stage 2: y2^T = Wt2 . X^T ; h = av + y2 ; X = bf16(swish3(h)) ----
    float4 pv[2];
#pragma unroll
    for (int m = 0; m < 2; ++m) {
        pa[m] = *reinterpret_cast<const float4*>(a3g + f0 + m * 16);
        pb[m] = *reinterpret_cast<const float4*>(be3g + f0 + m * 16);
        pv[m] = pos ? *reinterpret_cast<const float4*>(vp + f0 + m * 16)
                    : *reinterpret_cast<const float4*>(vm + f0 + m * 16);
    }
    __syncthreads();
    run_gemm(Wt2);
    float aln[4];
#pragma unroll
    for (int n = 0; n < 4; ++n) aln[n] = aLs[n * 16 + l15];
    __syncthreads();
#pragma unroll
    for (int m = 0; m < 2; ++m) {
        const int fm = f0 + m * 16;
#pragma unroll
        for (int n = 0; n < 4; ++n) {
            f32x4 y = acc[m][n];
            float h0 = fmaf(aln[n], pv[m].x, y[0]);
            float h1 = fmaf(aln[n], pv[m].y, y[1]);
            float h2 = fmaf(aln[n], pv[m].z, y[2]);
            float h3 = fmaf(aln[n], pv[m].w, y[3]);
            float s0 = pa[m].x * h0 * fast_sigm(pb[m].x * h0);
            float s1 = pa[m].y * h1 * fast_sigm(pb[m].y * h1);
            float s2 = pa[m].z * h2 * fast_sigm(pb[m].z * h2);
            float s3 = pa[m].w * h3 * fast_sigm(pb[m].w * h3);
            uint2 pk;
            pk.x = cvt_pk_bf16(s0, s1);
            pk.y = cvt_pk_bf16(s2, s3);
            *reinterpret_cast<uint2*>(&X[n * 16 + l15][fm]) = pk;
        }
    }

    // ---- stage 3: out^T = Wt3 . X^T + b_out ----
    float4 bb[2];
#pragma unroll
    for (int m = 0; m < 2; ++m)
        bb[m] = *reinterpret_cast<const float4*>(b_out + f0 + m * 16);
    __syncthreads();
    run_gemm(Wt3);
    float* obase = out + ((size_t)mol * NATOMS + l15) * FDIM + f0;
#pragma unroll
    for (int m = 0; m < 2; ++m) {
#pragma unroll
        for (int n = 0; n < 4; ++n) {
            float4 r;
            r.x = acc[m][n][0] + bb[m].x;
            r.y = acc[m][n][1] + bb[m].y;
            r.z = acc[m][n][2] + bb[m].z;
            r.w = acc[m][n][3] + bb[m].w;
            *reinterpret_cast<float4*>(obase + (size_t)n * 16 * FDIM + m * 16) = r;
        }
    }
}

extern "C" void kernel_launch(void* const* d_in, const int* in_sizes, int n_in,
                              void* d_out, int out_size, void* d_ws, size_t ws_size,
                              hipStream_t stream) {
    const float* psi     = (const float*)d_in[0];
    const float* e_z     = (const float*)d_in[1];
    // d_in[2] = num_atoms (uniformly 64)
    const float* W_lin   = (const float*)d_in[3];
    const float* b_lin   = (const float*)d_in[4];
    const float* k_plus  = (const float*)d_in[5];
    const float* k_minus = (const float*)d_in[6];
    const float* v_plus  = (const float*)d_in[7];
    const float* v_minus = (const float*)d_in[8];
    const float* W_r1    = (const float*)d_in[9];
    const float* W_r2    = (const float*)d_in[10];
    const float* W_out   = (const float*)d_in[11];
    const float* b_out   = (const float*)d_in[12];
    const float* a1      = (const float*)d_in[13];
    const float* be1     = (const float*)d_in[14];
    const float* a2      = (const float*)d_in[15];
    const float* be2     = (const float*)d_in[16];
    const float* a3      = (const float*)d_in[17];
    const float* be3     = (const float*)d_in[18];
    float* out = (float*)d_out;

    char* ws = (char*)d_ws;
    float* wkp = (float*)ws;
    float* wkm = wkp + FDIM;
    float* bk2 = wkm + FDIM;
    __hip_bfloat16* Wt1 = (__hip_bfloat16*)(ws + 4096);
    __hip_bfloat16* Wt2 = Wt1 + FDIM * FDIM;
    __hip_bfloat16* Wt3 = Wt2 + FDIM * FDIM;

    const int n_mol = in_sizes[0];

    prep_wk<<<FDIM, FDIM, 0, stream>>>(W_lin, b_lin, k_plus, k_minus, wkp, wkm, bk2);
    prep_wt<<<3 * FDIM, FDIM, 0, stream>>>(W_r1, W_r2, W_out, Wt1, Wt2, Wt3);
    fused_ee<<<n_mol, 512, 0, stream>>>(psi, e_z, wkp, wkm, bk2, v_plus, v_minus,
                                        Wt1, Wt2, Wt3, a1, be1, a2, be2, a3, be3,
                                        b_out, out);
}

// Round 4
// 277.045 us; speedup vs baseline: 1.4293x; 1.1269x over previous
//
#include <hip/hip_runtime.h>
#include <hip/hip_bf16.h>

#define FDIM 256
#define NATOMS 64
#define LDX 264  // row stride 528B: +4-dword shift per row spreads banks for b128 reads

using bf16x8 = __attribute__((ext_vector_type(8))) short;
using f32x4  = __attribute__((ext_vector_type(4))) float;

__device__ __forceinline__ float fast_sigm(float x) {
    return __builtin_amdgcn_rcpf(1.0f + __expf(-x));
}
__device__ __forceinline__ unsigned cvt_pk_bf16(float lo, float hi) {
    unsigned r;
    asm("v_cvt_pk_bf16_f32 %0, %1, %2" : "=v"(r) : "v"(lo), "v"(hi));
    return r;
}

// ---------------- prep 1: wk± = W_lin @ k±, bk± = b_lin . k± ----------------
__global__ void prep_wk(const float* __restrict__ W_lin, const float* __restrict__ b_lin,
                        const float* __restrict__ kp, const float* __restrict__ km,
                        float* __restrict__ wkp, float* __restrict__ wkm,
                        float* __restrict__ bk2) {
    const int f = blockIdx.x;
    const int t = threadIdx.x;
    __shared__ float sp[FDIM], sm[FDIM];
    float w = W_lin[(size_t)f * FDIM + t];
    sp[t] = w * kp[t];
    sm[t] = w * km[t];
    __syncthreads();
    for (int s = 128; s > 0; s >>= 1) {
        if (t < s) { sp[t] += sp[t + s]; sm[t] += sm[t + s]; }
        __syncthreads();
    }
    if (t == 0) { wkp[f] = sp[0]; wkm[f] = sm[0]; }
    if (f == 0) {
        __syncthreads();
        sp[t] = b_lin[t] * kp[t];
        sm[t] = b_lin[t] * km[t];
        __syncthreads();
        for (int s = 128; s > 0; s >>= 1) {
            if (t < s) { sp[t] += sp[t + s]; sm[t] += sm[t + s]; }
            __syncthreads();
        }
        if (t == 0) { bk2[0] = sp[0]; bk2[1] = sm[0]; }
    }
}

// ---------------- prep 2: Wt[n][k] = bf16(W[k][n]) ----------------
__global__ void prep_wt(const float* __restrict__ W1, const float* __restrict__ W2,
                        const float* __restrict__ W3,
                        __hip_bfloat16* __restrict__ Wt1, __hip_bfloat16* __restrict__ Wt2,
                        __hip_bfloat16* __restrict__ Wt3) {
    const int b = blockIdx.x;
    const int mat = b >> 8;
    const int n = b & 255;
    const int k = threadIdx.x;
    const float* W = (mat == 0) ? W1 : (mat == 1) ? W2 : W3;
    __hip_bfloat16* Wt = (mat == 0) ? Wt1 : (mat == 1) ? Wt2 : Wt3;
    Wt[(size_t)n * FDIM + k] = __float2bfloat16(W[(size_t)k * FDIM + n]);
}

// ---------------- fused: attention scalar a_i + 3-GEMM residual MLP ----------------
// 4 waves / molecule. Wave wv owns features [wv*64, wv*64+64) x all 64 atoms.
__global__ __launch_bounds__(256, 3) void fused_ee(
    const float* __restrict__ psi, const float* __restrict__ e_z,
    const float* __restrict__ wkp, const float* __restrict__ wkm,
    const float* __restrict__ bk2,
    const float* __restrict__ vp, const float* __restrict__ vm,
    const __hip_bfloat16* __restrict__ Wt1, const __hip_bfloat16* __restrict__ Wt2,
    const __hip_bfloat16* __restrict__ Wt3,
    const float* __restrict__ a1g, const float* __restrict__ be1g,
    const float* __restrict__ a2g, const float* __restrict__ be2g,
    const float* __restrict__ a3g, const float* __restrict__ be3g,
    const float* __restrict__ b_out, float* __restrict__ out) {

    __shared__ __hip_bfloat16 X[NATOMS][LDX];
    __shared__ float nums[NATOMS];

    const int tid = threadIdx.x;
    const int lane = tid & 63;
    const int wv = tid >> 6;       // 0..3
    const int l15 = lane & 15;
    const int hi4 = lane >> 4;     // 0..3
    const int mol = blockIdx.x;
    const float psiv = psi[mol];
    const bool pos = (psiv >= 0.0f);

    // ---- attention dots: batch-issue all 16 e_z row loads, then reduce ----
    {
        const float* wk = pos ? wkp : wkm;
        const float bk = pos ? bk2[0] : bk2[1];
        const float4 wkv = reinterpret_cast<const float4*>(wk)[lane];
        const float4* ez4 = reinterpret_cast<const float4*>(e_z + (size_t)mol * NATOMS * FDIM);
        float4 ev[16];
#pragma unroll
        for (int i = 0; i < 16; ++i) ev[i] = ez4[(size_t)(wv * 16 + i) * 64 + lane];
#pragma unroll
        for (int i = 0; i < 16; ++i) {
            float d = ev[i].x * wkv.x + ev[i].y * wkv.y + ev[i].z * wkv.z + ev[i].w * wkv.w;
#pragma unroll
            for (int off = 32; off > 0; off >>= 1) d += __shfl_xor(d, off, 64);
            if (lane == 0) nums[wv * 16 + i] = (d + bk) * 0.0625f;
        }
    }
    __syncthreads();

    // ---- redundant per-wave softmax: every wave computes all 64 a_i in regs ----
    float aL_reg;  // a_i for atom == lane
    {
        float arg = nums[lane];
        float nv = fmaxf(arg, 0.0f) + log1pf(__expf(-fabsf(arg)));
        float s = nv;
#pragma unroll
        for (int off = 32; off > 0; off >>= 1) s += __shfl_xor(s, off, 64);
        aL_reg = psiv * nv * __builtin_amdgcn_rcpf(s);
    }

    // ---- stage-1 input: X[r][c] = bf16(swish1(a_r * v_c)), rows wv*16..+16 ----
    {
        const int c0 = lane * 4;
        const int r0 = wv * 16;
        const float4 v4  = pos ? reinterpret_cast<const float4*>(vp)[lane]
                               : reinterpret_cast<const float4*>(vm)[lane];
        const float4 a14 = reinterpret_cast<const float4*>(a1g)[lane];
        const float4 b14 = reinterpret_cast<const float4*>(be1g)[lane];
#pragma unroll
        for (int i = 0; i < 16; ++i) {
            const float al = __shfl(aL_reg, r0 + i, 64);
            float x0 = al * v4.x, x1 = al * v4.y, x2 = al * v4.z, x3 = al * v4.w;
            float s0 = a14.x * x0 * fast_sigm(b14.x * x0);
            float s1 = a14.y * x1 * fast_sigm(b14.y * x1);
            float s2 = a14.z * x2 * fast_sigm(b14.z * x2);
            float s3 = a14.w * x3 * fast_sigm(b14.w * x3);
            uint2 pk;
            pk.x = cvt_pk_bf16(s0, s1);
            pk.y = cvt_pk_bf16(s2, s3);
            *reinterpret_cast<uint2*>(&X[r0 + i][c0]) = pk;
        }
    }

    // ---- GEMM machinery: A = Wt rows (L2), B = X rows (LDS) ----
    const int fbase = wv * 64 + l15;   // A-frag feature row (+ m*16)
    const int kg = hi4 * 8;            // k sub-offset within 32-wide k-step
    const int f0 = wv * 64 + hi4 * 4;  // C-frag feature base (+ m*16)
    const __hip_bfloat16* xbase = &X[l15][kg];

    f32x4 acc[4][4];
    const f32x4 zero = {0.f, 0.f, 0.f, 0.f};

    // 2-deep software pipeline on the weight fragments: L2 latency hides under MFMA
    auto run_gemm = [&](const __hip_bfloat16* __restrict__ Wt) {
        const __hip_bfloat16* wrow[4];
#pragma unroll
        for (int m = 0; m < 4; ++m) wrow[m] = Wt + (size_t)(fbase + m * 16) * FDIM + kg;
#pragma unroll
        for (int m = 0; m < 4; ++m)
#pragma unroll
            for (int n = 0; n < 4; ++n) acc[m][n] = zero;
        bf16x8 wa[4], wn[4];
#pragma unroll
        for (int m = 0; m < 4; ++m) wa[m] = *reinterpret_cast<const bf16x8*>(wrow[m]);
#pragma unroll
        for (int k0 = 0; k0 < 8; ++k0) {
            if (k0 < 7) {
#pragma unroll
                for (int m = 0; m < 4; ++m)
                    wn[m] = *reinterpret_cast<const bf16x8*>(wrow[m] + (k0 + 1) * 32);
            }
            bf16x8 bfr[4];
#pragma unroll
            for (int n = 0; n < 4; ++n)
                bfr[n] = *reinterpret_cast<const bf16x8*>(xbase + n * (16 * LDX) + k0 * 32);
#pragma unroll
            for (int m = 0; m < 4; ++m)
#pragma unroll
                for (int n = 0; n < 4; ++n)
                    acc[m][n] =
                        __builtin_amdgcn_mfma_f32_16x16x32_bf16(wa[m], bfr[n], acc[m][n], 0, 0, 0);
#pragma unroll
            for (int m = 0; m < 4; ++m) wa[m] = wn[m];
        }
    };

    __syncthreads();

    // ---- stage 1: y1^T = Wt1 . X^T ; X = bf16(swish2(y1)) ----
    run_gemm(Wt1);
    float4 pa[4], pb[4];
#pragma unroll
    for (int m = 0; m < 4; ++m) {  // issue param loads; latency overlaps barrier wait
        pa[m] = *reinterpret_cast<const float4*>(a2g + f0 + m * 16);
        pb[m] = *reinterpret_cast<const float4*>(be2g + f0 + m * 16);
    }
    __syncthreads();
#pragma unroll
    for (int m = 0; m < 4; ++m) {
        const int fm = f0 + m * 16;
#pragma unroll
        for (int n = 0; n < 4; ++n) {
            f32x4 y = acc[m][n];
            float s0 = pa[m].x * y[0] * fast_sigm(pb[m].x * y[0]);
            float s1 = pa[m].y * y[1] * fast_sigm(pb[m].y * y[1]);
            float s2 = pa[m].z * y[2] * fast_sigm(pb[m].z * y[2]);
            float s3 = pa[m].w * y[3] * fast_sigm(pb[m].w * y[3]);
            uint2 pk;
            pk.x = cvt_pk_bf16(s0, s1);
            pk.y = cvt_pk_bf16(s2, s3);
            *reinterpret_cast<uint2*>(&X[n * 16 + l15][fm]) = pk;
        }
    }
    __syncthreads();

    // ---- stage 2: y2^T = Wt2 . X^T ; h = av + y2 ; X = bf16(swish3(h)) ----
    run_gemm(Wt2);
    float4 pv[4];
#pragma unroll
    for (int m = 0; m < 4; ++m) {
        pa[m] = *reinterpret_cast<const float4*>(a3g + f0 + m * 16);
        pb[m] = *reinterpret_cast<const float4*>(be3g + f0 + m * 16);
        pv[m] = pos ? *reinterpret_cast<const float4*>(vp + f0 + m * 16)
                    : *reinterpret_cast<const float4*>(vm + f0 + m * 16);
    }
    float aln[4];
#pragma unroll
    for (int n = 0; n < 4; ++n) aln[n] = __shfl(aL_reg, n * 16 + l15, 64);
    __syncthreads();
#pragma unroll
    for (int m = 0; m < 4; ++m) {
        const int fm = f0 + m * 16;
#pragma unroll
        for (int n = 0; n < 4; ++n) {
            f32x4 y = acc[m][n];
            float h0 = fmaf(aln[n], pv[m].x, y[0]);
            float h1 = fmaf(aln[n], pv[m].y, y[1]);
            float h2 = fmaf(aln[n], pv[m].z, y[2]);
            float h3 = fmaf(aln[n], pv[m].w, y[3]);
            float s0 = pa[m].x * h0 * fast_sigm(pb[m].x * h0);
            float s1 = pa[m].y * h1 * fast_sigm(pb[m].y * h1);
            float s2 = pa[m].z * h2 * fast_sigm(pb[m].z * h2);
            float s3 = pa[m].w * h3 * fast_sigm(pb[m].w * h3);
            uint2 pk;
            pk.x = cvt_pk_bf16(s0, s1);
            pk.y = cvt_pk_bf16(s2, s3);
            *reinterpret_cast<uint2*>(&X[n * 16 + l15][fm]) = pk;
        }
    }
    __syncthreads();

    // ---- stage 3: out^T = Wt3 . X^T + b_out ; n-outer/m-inner fills full 128B lines ----
    run_gemm(Wt3);
    float4 bb[4];
#pragma unroll
    for (int m = 0; m < 4; ++m)
        bb[m] = *reinterpret_cast<const float4*>(b_out + f0 + m * 16);
#pragma unroll
    for (int n = 0; n < 4; ++n) {
        float* orow = out + ((size_t)mol * NATOMS + n * 16 + l15) * FDIM + f0;
#pragma unroll
        for (int m = 0; m < 4; ++m) {
            float4 r;
            r.x = acc[m][n][0] + bb[m].x;
            r.y = acc[m][n][1] + bb[m].y;
            r.z = acc[m][n][2] + bb[m].z;
            r.w = acc[m][n][3] + bb[m].w;
            *reinterpret_cast<float4*>(orow + m * 16) = r;
        }
    }
}

extern "C" void kernel_launch(void* const* d_in, const int* in_sizes, int n_in,
                              void* d_out, int out_size, void* d_ws, size_t ws_size,
                              hipStream_t stream) {
    const float* psi     = (const float*)d_in[0];
    const float* e_z     = (const float*)d_in[1];
    // d_in[2] = num_atoms (uniformly 64)
    const float* W_lin   = (const float*)d_in[3];
    const float* b_lin   = (const float*)d_in[4];
    const float* k_plus  = (const float*)d_in[5];
    const float* k_minus = (const float*)d_in[6];
    const float* v_plus  = (const float*)d_in[7];
    const float* v_minus = (const float*)d_in[8];
    const float* W_r1    = (const float*)d_in[9];
    const float* W_r2    = (const float*)d_in[10];
    const float* W_out   = (const float*)d_in[11];
    const float* b_out   = (const float*)d_in[12];
    const float* a1      = (const float*)d_in[13];
    const float* be1     = (const float*)d_in[14];
    const float* a2      = (const float*)d_in[15];
    const float* be2     = (const float*)d_in[16];
    const float* a3      = (const float*)d_in[17];
    const float* be3     = (const float*)d_in[18];
    float* out = (float*)d_out;

    char* ws = (char*)d_ws;
    float* wkp = (float*)ws;
    float* wkm = wkp + FDIM;
    float* bk2 = wkm + FDIM;
    __hip_bfloat16* Wt1 = (__hip_bfloat16*)(ws + 4096);
    __hip_bfloat16* Wt2 = Wt1 + FDIM * FDIM;
    __hip_bfloat16* Wt3 = Wt2 + FDIM * FDIM;

    const int n_mol = in_sizes[0];

    prep_wk<<<FDIM, FDIM, 0, stream>>>(W_lin, b_lin, k_plus, k_minus, wkp, wkm, bk2);
    prep_wt<<<3 * FDIM, FDIM, 0, stream>>>(W_r1, W_r2, W_out, Wt1, Wt2, Wt3);
    fused_ee<<<n_mol, 256, 0, stream>>>(psi, e_z, wkp, wkm, bk2, v_plus, v_minus,
                                        Wt1, Wt2, Wt3, a1, be1, a2, be2, a3, be3,
                                        b_out, out);
}

// Round 5
// 229.342 us; speedup vs baseline: 1.7266x; 1.2080x over previous
//
#include <hip/hip_runtime.h>
#include <hip/hip_bf16.h>

#define FDIM 256
#define NATOMS 64
#define LDX 264  // row stride 528B: +4-dword shift per row spreads banks for b128 reads

using bf16x8 = __attribute__((ext_vector_type(8))) short;
using f32x4  = __attribute__((ext_vector_type(4))) float;

__device__ __forceinline__ float fast_sigm(float x) {
    return __builtin_amdgcn_rcpf(1.0f + __expf(-x));
}
__device__ __forceinline__ unsigned cvt_pk_bf16(float lo, float hi) {
    unsigned r;
    asm("v_cvt_pk_bf16_f32 %0, %1, %2" : "=v"(r) : "v"(lo), "v"(hi));
    return r;
}

// ---------------- prep 1: wk± = W_lin @ k±, bk± = b_lin . k± ----------------
__global__ void prep_wk(const float* __restrict__ W_lin, const float* __restrict__ b_lin,
                        const float* __restrict__ kp, const float* __restrict__ km,
                        float* __restrict__ wkp, float* __restrict__ wkm,
                        float* __restrict__ bk2) {
    const int f = blockIdx.x;
    const int t = threadIdx.x;
    __shared__ float sp[FDIM], sm[FDIM];
    float w = W_lin[(size_t)f * FDIM + t];
    sp[t] = w * kp[t];
    sm[t] = w * km[t];
    __syncthreads();
    for (int s = 128; s > 0; s >>= 1) {
        if (t < s) { sp[t] += sp[t + s]; sm[t] += sm[t + s]; }
        __syncthreads();
    }
    if (t == 0) { wkp[f] = sp[0]; wkm[f] = sm[0]; }
    if (f == 0) {
        __syncthreads();
        sp[t] = b_lin[t] * kp[t];
        sm[t] = b_lin[t] * km[t];
        __syncthreads();
        for (int s = 128; s > 0; s >>= 1) {
            if (t < s) { sp[t] += sp[t + s]; sm[t] += sm[t + s]; }
            __syncthreads();
        }
        if (t == 0) { bk2[0] = sp[0]; bk2[1] = sm[0]; }
    }
}

// ---------------- prep 2: Wt[n][k] = bf16(W[k][n]) ----------------
__global__ void prep_wt(const float* __restrict__ W1, const float* __restrict__ W2,
                        const float* __restrict__ W3,
                        __hip_bfloat16* __restrict__ Wt1, __hip_bfloat16* __restrict__ Wt2,
                        __hip_bfloat16* __restrict__ Wt3) {
    const int b = blockIdx.x;
    const int mat = b >> 8;
    const int n = b & 255;
    const int k = threadIdx.x;
    const float* W = (mat == 0) ? W1 : (mat == 1) ? W2 : W3;
    __hip_bfloat16* Wt = (mat == 0) ? Wt1 : (mat == 1) ? Wt2 : Wt3;
    Wt[(size_t)n * FDIM + k] = __float2bfloat16(W[(size_t)k * FDIM + n]);
}

// ---------------- fused: 2 molecules / block, 4 waves ----------------
// Wave wv owns features [wv*64, wv*64+64) x 64 atoms x 2 molecules.
// Weight fragments loaded once per block feed BOTH molecules (halves L2 traffic,
// and 32 MFMAs/k-step fully cover L2 latency).
__global__ __launch_bounds__(256, 2) void fused_ee(
    const float* __restrict__ psi, const float* __restrict__ e_z,
    const float* __restrict__ wkp, const float* __restrict__ wkm,
    const float* __restrict__ bk2,
    const float* __restrict__ vp, const float* __restrict__ vm,
    const __hip_bfloat16* __restrict__ Wt1, const __hip_bfloat16* __restrict__ Wt2,
    const __hip_bfloat16* __restrict__ Wt3,
    const float* __restrict__ a1g, const float* __restrict__ be1g,
    const float* __restrict__ a2g, const float* __restrict__ be2g,
    const float* __restrict__ a3g, const float* __restrict__ be3g,
    const float* __restrict__ b_out, float* __restrict__ out) {

    __shared__ __hip_bfloat16 X[2][NATOMS][LDX];
    __shared__ float nums[2][NATOMS];

    const int tid = threadIdx.x;
    const int lane = tid & 63;
    const int wv = tid >> 6;       // 0..3
    const int l15 = lane & 15;
    const int hi4 = lane >> 4;     // 0..3
    const int mol0 = blockIdx.x * 2;
    const int mol1 = mol0 + 1;
    const float psv0 = psi[mol0], psv1 = psi[mol1];
    const bool pos0 = (psv0 >= 0.0f), pos1 = (psv1 >= 0.0f);

    // ---- attention dots: batch-issue 32 e_z row loads (16/mol), then reduce ----
    {
        const float4 wkv0 = pos0 ? reinterpret_cast<const float4*>(wkp)[lane]
                                 : reinterpret_cast<const float4*>(wkm)[lane];
        const float4 wkv1 = pos1 ? reinterpret_cast<const float4*>(wkp)[lane]
                                 : reinterpret_cast<const float4*>(wkm)[lane];
        const float bkA = pos0 ? bk2[0] : bk2[1];
        const float bkB = pos1 ? bk2[0] : bk2[1];
        const float4* ez4 = reinterpret_cast<const float4*>(e_z);
        float4 ev[32];
#pragma unroll
        for (int i = 0; i < 16; ++i)
            ev[i] = ez4[(size_t)(mol0 * NATOMS + wv * 16 + i) * 64 + lane];
#pragma unroll
        for (int i = 0; i < 16; ++i)
            ev[16 + i] = ez4[(size_t)(mol1 * NATOMS + wv * 16 + i) * 64 + lane];
#pragma unroll
        for (int p = 0; p < 2; ++p) {
            const float4 wkv = p ? wkv1 : wkv0;
            const float bk = p ? bkB : bkA;
#pragma unroll
            for (int i = 0; i < 16; ++i) {
                const float4 e = ev[p * 16 + i];
                float d = e.x * wkv.x + e.y * wkv.y + e.z * wkv.z + e.w * wkv.w;
#pragma unroll
                for (int off = 32; off > 0; off >>= 1) d += __shfl_xor(d, off, 64);
                if (lane == 0) nums[p][wv * 16 + i] = (d + bk) * 0.0625f;
            }
        }
    }
    __syncthreads();

    // ---- redundant per-wave softmax for both molecules ----
    float aL0, aL1;  // a_i for atom == lane, mol 0/1
    {
        float arg0 = nums[0][lane], arg1 = nums[1][lane];
        float nv0 = fmaxf(arg0, 0.0f) + log1pf(__expf(-fabsf(arg0)));
        float nv1 = fmaxf(arg1, 0.0f) + log1pf(__expf(-fabsf(arg1)));
        float s0 = nv0, s1 = nv1;
#pragma unroll
        for (int off = 32; off > 0; off >>= 1) {
            s0 += __shfl_xor(s0, off, 64);
            s1 += __shfl_xor(s1, off, 64);
        }
        aL0 = psv0 * nv0 * __builtin_amdgcn_rcpf(s0);
        aL1 = psv1 * nv1 * __builtin_amdgcn_rcpf(s1);
    }

    // ---- stage-1 input: X[p][r][c] = bf16(swish1(a_r * v_c)), rows wv*16..+16 ----
    {
        const int c0 = lane * 4;
        const int r0 = wv * 16;
        const float4 v40 = pos0 ? reinterpret_cast<const float4*>(vp)[lane]
                                : reinterpret_cast<const float4*>(vm)[lane];
        const float4 v41 = pos1 ? reinterpret_cast<const float4*>(vp)[lane]
                                : reinterpret_cast<const float4*>(vm)[lane];
        const float4 a14 = reinterpret_cast<const float4*>(a1g)[lane];
        const float4 b14 = reinterpret_cast<const float4*>(be1g)[lane];
#pragma unroll
        for (int i = 0; i < 16; ++i) {
            const float al0 = __shfl(aL0, r0 + i, 64);
            const float al1 = __shfl(aL1, r0 + i, 64);
            float x0 = al0 * v40.x, x1 = al0 * v40.y, x2 = al0 * v40.z, x3 = al0 * v40.w;
            float y0 = al1 * v41.x, y1 = al1 * v41.y, y2 = al1 * v41.z, y3 = al1 * v41.w;
            uint2 pk0, pk1;
            pk0.x = cvt_pk_bf16(a14.x * x0 * fast_sigm(b14.x * x0),
                                a14.y * x1 * fast_sigm(b14.y * x1));
            pk0.y = cvt_pk_bf16(a14.z * x2 * fast_sigm(b14.z * x2),
                                a14.w * x3 * fast_sigm(b14.w * x3));
            pk1.x = cvt_pk_bf16(a14.x * y0 * fast_sigm(b14.x * y0),
                                a14.y * y1 * fast_sigm(b14.y * y1));
            pk1.y = cvt_pk_bf16(a14.z * y2 * fast_sigm(b14.z * y2),
                                a14.w * y3 * fast_sigm(b14.w * y3));
            *reinterpret_cast<uint2*>(&X[0][r0 + i][c0]) = pk0;
            *reinterpret_cast<uint2*>(&X[1][r0 + i][c0]) = pk1;
        }
    }

    // ---- GEMM machinery: A = Wt rows (L2, shared across mols), B = X rows (LDS) ----
    const int fbase = wv * 64 + l15;   // A-frag feature row (+ m*16)
    const int kg = hi4 * 8;            // k sub-offset within 32-wide k-step
    const int f0 = wv * 64 + hi4 * 4;  // C-frag feature base (+ m*16)
    const __hip_bfloat16* xbase0 = &X[0][l15][kg];
    const __hip_bfloat16* xbase1 = &X[1][l15][kg];

    f32x4 acc[2][4][4];  // [mol][m][n]
    const f32x4 zero = {0.f, 0.f, 0.f, 0.f};

    auto run_gemm = [&](const __hip_bfloat16* __restrict__ Wt) {
        const __hip_bfloat16* wrow[4];
#pragma unroll
        for (int m = 0; m < 4; ++m) wrow[m] = Wt + (size_t)(fbase + m * 16) * FDIM + kg;
#pragma unroll
        for (int p = 0; p < 2; ++p)
#pragma unroll
            for (int m = 0; m < 4; ++m)
#pragma unroll
                for (int n = 0; n < 4; ++n) acc[p][m][n] = zero;
        bf16x8 wa[4], wn[4];
#pragma unroll
        for (int m = 0; m < 4; ++m) wa[m] = *reinterpret_cast<const bf16x8*>(wrow[m]);
#pragma unroll
        for (int k0 = 0; k0 < 8; ++k0) {
            if (k0 < 7) {
#pragma unroll
                for (int m = 0; m < 4; ++m)
                    wn[m] = *reinterpret_cast<const bf16x8*>(wrow[m] + (k0 + 1) * 32);
            }
            bf16x8 ba[4], bb[4];
#pragma unroll
            for (int n = 0; n < 4; ++n) {
                ba[n] = *reinterpret_cast<const bf16x8*>(xbase0 + n * (16 * LDX) + k0 * 32);
                bb[n] = *reinterpret_cast<const bf16x8*>(xbase1 + n * (16 * LDX) + k0 * 32);
            }
#pragma unroll
            for (int m = 0; m < 4; ++m)
#pragma unroll
                for (int n = 0; n < 4; ++n)
                    acc[0][m][n] =
                        __builtin_amdgcn_mfma_f32_16x16x32_bf16(wa[m], ba[n], acc[0][m][n], 0, 0, 0);
#pragma unroll
            for (int m = 0; m < 4; ++m)
#pragma unroll
                for (int n = 0; n < 4; ++n)
                    acc[1][m][n] =
                        __builtin_amdgcn_mfma_f32_16x16x32_bf16(wa[m], bb[n], acc[1][m][n], 0, 0, 0);
#pragma unroll
            for (int m = 0; m < 4; ++m) wa[m] = wn[m];
        }
    };

    __syncthreads();

    // ---- stage 1: y1^T = Wt1 . X^T ; X = bf16(swish2(y1)) ----
    run_gemm(Wt1);
    float4 pa[4], pb[4];
#pragma unroll
    for (int m = 0; m < 4; ++m) {  // param-load latency overlaps barrier wait
        pa[m] = *reinterpret_cast<const float4*>(a2g + f0 + m * 16);
        pb[m] = *reinterpret_cast<const float4*>(be2g + f0 + m * 16);
    }
    __syncthreads();
#pragma unroll
    for (int p = 0; p < 2; ++p)
#pragma unroll
        for (int m = 0; m < 4; ++m) {
            const int fm = f0 + m * 16;
#pragma unroll
            for (int n = 0; n < 4; ++n) {
                f32x4 y = acc[p][m][n];
                float s0 = pa[m].x * y[0] * fast_sigm(pb[m].x * y[0]);
                float s1 = pa[m].y * y[1] * fast_sigm(pb[m].y * y[1]);
                float s2 = pa[m].z * y[2] * fast_sigm(pb[m].z * y[2]);
                float s3 = pa[m].w * y[3] * fast_sigm(pb[m].w * y[3]);
                uint2 pk;
                pk.x = cvt_pk_bf16(s0, s1);
                pk.y = cvt_pk_bf16(s2, s3);
                *reinterpret_cast<uint2*>(&X[p][n * 16 + l15][fm]) = pk;
            }
        }
    __syncthreads();

    // ---- stage 2: y2^T = Wt2 . X^T ; h = av + y2 ; X = bf16(swish3(h)) ----
    run_gemm(Wt2);
    float4 pv0[4], pv1[4];
#pragma unroll
    for (int m = 0; m < 4; ++m) {
        pa[m] = *reinterpret_cast<const float4*>(a3g + f0 + m * 16);
        pb[m] = *reinterpret_cast<const float4*>(be3g + f0 + m * 16);
        pv0[m] = pos0 ? *reinterpret_cast<const float4*>(vp + f0 + m * 16)
                      : *reinterpret_cast<const float4*>(vm + f0 + m * 16);
        pv1[m] = pos1 ? *reinterpret_cast<const float4*>(vp + f0 + m * 16)
                      : *reinterpret_cast<const float4*>(vm + f0 + m * 16);
    }
    float aln0[4], aln1[4];
#pragma unroll
    for (int n = 0; n < 4; ++n) {
        aln0[n] = __shfl(aL0, n * 16 + l15, 64);
        aln1[n] = __shfl(aL1, n * 16 + l15, 64);
    }
    __syncthreads();
#pragma unroll
    for (int p = 0; p < 2; ++p)
#pragma unroll
        for (int m = 0; m < 4; ++m) {
            const int fm = f0 + m * 16;
            const float4 pv = p ? pv1[m] : pv0[m];
#pragma unroll
            for (int n = 0; n < 4; ++n) {
                const float al = p ? aln1[n] : aln0[n];
                f32x4 y = acc[p][m][n];
                float h0 = fmaf(al, pv.x, y[0]);
                float h1 = fmaf(al, pv.y, y[1]);
                float h2 = fmaf(al, pv.z, y[2]);
                float h3 = fmaf(al, pv.w, y[3]);
                float s0 = pa[m].x * h0 * fast_sigm(pb[m].x * h0);
                float s1 = pa[m].y * h1 * fast_sigm(pb[m].y * h1);
                float s2 = pa[m].z * h2 * fast_sigm(pb[m].z * h2);
                float s3 = pa[m].w * h3 * fast_sigm(pb[m].w * h3);
                uint2 pk;
                pk.x = cvt_pk_bf16(s0, s1);
                pk.y = cvt_pk_bf16(s2, s3);
                *reinterpret_cast<uint2*>(&X[p][n * 16 + l15][fm]) = pk;
            }
        }
    __syncthreads();

    // ---- stage 3: out^T = Wt3 . X^T + b_out ; n-outer/m-inner fills 128B lines ----
    run_gemm(Wt3);
    float4 bbv[4];
#pragma unroll
    for (int m = 0; m < 4; ++m)
        bbv[m] = *reinterpret_cast<const float4*>(b_out + f0 + m * 16);
#pragma unroll
    for (int p = 0; p < 2; ++p) {
        const int mol = p ? mol1 : mol0;
#pragma unroll
        for (int n = 0; n < 4; ++n) {
            float* orow = out + ((size_t)mol * NATOMS + n * 16 + l15) * FDIM + f0;
#pragma unroll
            for (int m = 0; m < 4; ++m) {
                float4 r;
                r.x = acc[p][m][n][0] + bbv[m].x;
                r.y = acc[p][m][n][1] + bbv[m].y;
                r.z = acc[p][m][n][2] + bbv[m].z;
                r.w = acc[p][m][n][3] + bbv[m].w;
                *reinterpret_cast<float4*>(orow + m * 16) = r;
            }
        }
    }
}

extern "C" void kernel_launch(void* const* d_in, const int* in_sizes, int n_in,
                              void* d_out, int out_size, void* d_ws, size_t ws_size,
                              hipStream_t stream) {
    const float* psi     = (const float*)d_in[0];
    const float* e_z     = (const float*)d_in[1];
    // d_in[2] = num_atoms (uniformly 64)
    const float* W_lin   = (const float*)d_in[3];
    const float* b_lin   = (const float*)d_in[4];
    const float* k_plus  = (const float*)d_in[5];
    const float* k_minus = (const float*)d_in[6];
    const float* v_plus  = (const float*)d_in[7];
    const float* v_minus = (const float*)d_in[8];
    const float* W_r1    = (const float*)d_in[9];
    const float* W_r2    = (const float*)d_in[10];
    const float* W_out   = (const float*)d_in[11];
    const float* b_out   = (const float*)d_in[12];
    const float* a1      = (const float*)d_in[13];
    const float* be1     = (const float*)d_in[14];
    const float* a2      = (const float*)d_in[15];
    const float* be2     = (const float*)d_in[16];
    const float* a3      = (const float*)d_in[17];
    const float* be3     = (const float*)d_in[18];
    float* out = (float*)d_out;

    char* ws = (char*)d_ws;
    float* wkp = (float*)ws;
    float* wkm = wkp + FDIM;
    float* bk2 = wkm + FDIM;
    __hip_bfloat16* Wt1 = (__hip_bfloat16*)(ws + 4096);
    __hip_bfloat16* Wt2 = Wt1 + FDIM * FDIM;
    __hip_bfloat16* Wt3 = Wt2 + FDIM * FDIM;

    const int n_mol = in_sizes[0];

    prep_wk<<<FDIM, FDIM, 0, stream>>>(W_lin, b_lin, k_plus, k_minus, wkp, wkm, bk2);
    prep_wt<<<3 * FDIM, FDIM, 0, stream>>>(W_r1, W_r2, W_out, Wt1, Wt2, Wt3);
    fused_ee<<<n_mol / 2, 256, 0, stream>>>(psi, e_z, wkp, wkm, bk2, v_plus, v_minus,
                                            Wt1, Wt2, Wt3, a1, be1, a2, be2, a3, be3,
                                            b_out, out);
}

// Round 6
// 226.934 us; speedup vs baseline: 1.7450x; 1.0106x over previous
//
#include <hip/hip_runtime.h>
#include <hip/hip_bf16.h>

#define FDIM 256
#define NATOMS 64
#define LDX 264  // row stride 528B: +4-dword shift per row spreads banks for b128 reads

using bf16x8 = __attribute__((ext_vector_type(8))) short;
using f32x4  = __attribute__((ext_vector_type(4))) float;

__device__ __forceinline__ float fast_sigm(float x) {
    return __builtin_amdgcn_rcpf(1.0f + __expf(-x));
}
__device__ __forceinline__ unsigned cvt_pk_bf16(float lo, float hi) {
    unsigned r;
    asm("v_cvt_pk_bf16_f32 %0, %1, %2" : "=v"(r) : "v"(lo), "v"(hi));
    return r;
}

// ---------------- prep 1: wk± = W_lin @ k±, bk± = b_lin . k± ----------------
__global__ void prep_wk(const float* __restrict__ W_lin, const float* __restrict__ b_lin,
                        const float* __restrict__ kp, const float* __restrict__ km,
                        float* __restrict__ wkp, float* __restrict__ wkm,
                        float* __restrict__ bk2) {
    const int f = blockIdx.x;
    const int t = threadIdx.x;
    __shared__ float sp[FDIM], sm[FDIM];
    float w = W_lin[(size_t)f * FDIM + t];
    sp[t] = w * kp[t];
    sm[t] = w * km[t];
    __syncthreads();
    for (int s = 128; s > 0; s >>= 1) {
        if (t < s) { sp[t] += sp[t + s]; sm[t] += sm[t + s]; }
        __syncthreads();
    }
    if (t == 0) { wkp[f] = sp[0]; wkm[f] = sm[0]; }
    if (f == 0) {
        __syncthreads();
        sp[t] = b_lin[t] * kp[t];
        sm[t] = b_lin[t] * km[t];
        __syncthreads();
        for (int s = 128; s > 0; s >>= 1) {
            if (t < s) { sp[t] += sp[t + s]; sm[t] += sm[t + s]; }
            __syncthreads();
        }
        if (t == 0) { bk2[0] = sp[0]; bk2[1] = sm[0]; }
    }
}

// ---------------- prep 2: Wt[n][k] = bf16(W[k][n]) ----------------
__global__ void prep_wt(const float* __restrict__ W1, const float* __restrict__ W2,
                        const float* __restrict__ W3,
                        __hip_bfloat16* __restrict__ Wt1, __hip_bfloat16* __restrict__ Wt2,
                        __hip_bfloat16* __restrict__ Wt3) {
    const int b = blockIdx.x;
    const int mat = b >> 8;
    const int n = b & 255;
    const int k = threadIdx.x;
    const float* W = (mat == 0) ? W1 : (mat == 1) ? W2 : W3;
    __hip_bfloat16* Wt = (mat == 0) ? Wt1 : (mat == 1) ? Wt2 : Wt3;
    Wt[(size_t)n * FDIM + k] = __float2bfloat16(W[(size_t)k * FDIM + n]);
}

// ---------------- fused: 2 molecules / block, 8 waves ----------------
// Wave wv owns features [wv*32, wv*32+32) x 64 atoms x 2 molecules.
__global__ __launch_bounds__(512, 4) void fused_ee(
    const float* __restrict__ psi, const float* __restrict__ e_z,
    const float* __restrict__ wkp, const float* __restrict__ wkm,
    const float* __restrict__ bk2,
    const float* __restrict__ vp, const float* __restrict__ vm,
    const __hip_bfloat16* __restrict__ Wt1, const __hip_bfloat16* __restrict__ Wt2,
    const __hip_bfloat16* __restrict__ Wt3,
    const float* __restrict__ a1g, const float* __restrict__ be1g,
    const float* __restrict__ a2g, const float* __restrict__ be2g,
    const float* __restrict__ a3g, const float* __restrict__ be3g,
    const float* __restrict__ b_out, float* __restrict__ out) {

    __shared__ __hip_bfloat16 X[2][NATOMS][LDX];
    __shared__ float nums[2][NATOMS];

    const int tid = threadIdx.x;
    const int lane = tid & 63;
    const int wv = tid >> 6;       // 0..7
    const int l15 = lane & 15;
    const int hi4 = lane >> 4;     // 0..3
    const int mol0 = blockIdx.x * 2;
    const int mol1 = mol0 + 1;
    const float psv0 = psi[mol0], psv1 = psi[mol1];
    const bool pos0 = (psv0 >= 0.0f), pos1 = (psv1 >= 0.0f);

    // ---- attention dots: batch-issue 16 e_z row loads (8/mol), then reduce ----
    {
        const float4 wkv0 = pos0 ? reinterpret_cast<const float4*>(wkp)[lane]
                                 : reinterpret_cast<const float4*>(wkm)[lane];
        const float4 wkv1 = pos1 ? reinterpret_cast<const float4*>(wkp)[lane]
                                 : reinterpret_cast<const float4*>(wkm)[lane];
        const float bkA = pos0 ? bk2[0] : bk2[1];
        const float bkB = pos1 ? bk2[0] : bk2[1];
        const float4* ez4 = reinterpret_cast<const float4*>(e_z);
        float4 ev[16];
#pragma unroll
        for (int i = 0; i < 8; ++i)
            ev[i] = ez4[(size_t)(mol0 * NATOMS + wv * 8 + i) * 64 + lane];
#pragma unroll
        for (int i = 0; i < 8; ++i)
            ev[8 + i] = ez4[(size_t)(mol1 * NATOMS + wv * 8 + i) * 64 + lane];
#pragma unroll
        for (int p = 0; p < 2; ++p) {
            const float4 wkv = p ? wkv1 : wkv0;
            const float bk = p ? bkB : bkA;
#pragma unroll
            for (int i = 0; i < 8; ++i) {
                const float4 e = ev[p * 8 + i];
                float d = e.x * wkv.x + e.y * wkv.y + e.z * wkv.z + e.w * wkv.w;
#pragma unroll
                for (int off = 32; off > 0; off >>= 1) d += __shfl_xor(d, off, 64);
                if (lane == 0) nums[p][wv * 8 + i] = (d + bk) * 0.0625f;
            }
        }
    }
    __syncthreads();

    // ---- redundant per-wave softmax for both molecules ----
    float aL0, aL1;  // a_i for atom == lane
    {
        float arg0 = nums[0][lane], arg1 = nums[1][lane];
        float nv0 = fmaxf(arg0, 0.0f) + log1pf(__expf(-fabsf(arg0)));
        float nv1 = fmaxf(arg1, 0.0f) + log1pf(__expf(-fabsf(arg1)));
        float s0 = nv0, s1 = nv1;
#pragma unroll
        for (int off = 32; off > 0; off >>= 1) {
            s0 += __shfl_xor(s0, off, 64);
            s1 += __shfl_xor(s1, off, 64);
        }
        aL0 = psv0 * nv0 * __builtin_amdgcn_rcpf(s0);
        aL1 = psv1 * nv1 * __builtin_amdgcn_rcpf(s1);
    }

    // ---- stage-1 input: X[p][r][c] = bf16(swish1(a_r * v_c)), rows wv*8..+8 ----
    {
        const int c0 = lane * 4;
        const int r0 = wv * 8;
        const float4 v40 = pos0 ? reinterpret_cast<const float4*>(vp)[lane]
                                : reinterpret_cast<const float4*>(vm)[lane];
        const float4 v41 = pos1 ? reinterpret_cast<const float4*>(vp)[lane]
                                : reinterpret_cast<const float4*>(vm)[lane];
        const float4 a14 = reinterpret_cast<const float4*>(a1g)[lane];
        const float4 b14 = reinterpret_cast<const float4*>(be1g)[lane];
#pragma unroll
        for (int i = 0; i < 8; ++i) {
            const float al0 = __shfl(aL0, r0 + i, 64);
            const float al1 = __shfl(aL1, r0 + i, 64);
            float x0 = al0 * v40.x, x1 = al0 * v40.y, x2 = al0 * v40.z, x3 = al0 * v40.w;
            float y0 = al1 * v41.x, y1 = al1 * v41.y, y2 = al1 * v41.z, y3 = al1 * v41.w;
            uint2 pk0, pk1;
            pk0.x = cvt_pk_bf16(a14.x * x0 * fast_sigm(b14.x * x0),
                                a14.y * x1 * fast_sigm(b14.y * x1));
            pk0.y = cvt_pk_bf16(a14.z * x2 * fast_sigm(b14.z * x2),
                                a14.w * x3 * fast_sigm(b14.w * x3));
            pk1.x = cvt_pk_bf16(a14.x * y0 * fast_sigm(b14.x * y0),
                                a14.y * y1 * fast_sigm(b14.y * y1));
            pk1.y = cvt_pk_bf16(a14.z * y2 * fast_sigm(b14.z * y2),
                                a14.w * y3 * fast_sigm(b14.w * y3));
            *reinterpret_cast<uint2*>(&X[0][r0 + i][c0]) = pk0;
            *reinterpret_cast<uint2*>(&X[1][r0 + i][c0]) = pk1;
        }
    }

    // ---- GEMM machinery: A = Wt rows (L2, shared across mols), B = X rows (LDS) ----
    const int fbase = wv * 32 + l15;   // A-frag feature row (+ m*16)
    const int kg = hi4 * 8;            // k sub-offset within 32-wide k-step
    const int f0 = wv * 32 + hi4 * 4;  // C-frag feature base (+ m*16)
    const __hip_bfloat16* xbase0 = &X[0][l15][kg];
    const __hip_bfloat16* xbase1 = &X[1][l15][kg];

    f32x4 acc[2][2][4];  // [mol][m][n]
    const f32x4 zero = {0.f, 0.f, 0.f, 0.f};

    auto run_gemm = [&](const __hip_bfloat16* __restrict__ Wt) {
        const __hip_bfloat16* wrow0 = Wt + (size_t)fbase * FDIM + kg;
        const __hip_bfloat16* wrow1 = wrow0 + 16 * FDIM;
#pragma unroll
        for (int p = 0; p < 2; ++p)
#pragma unroll
            for (int m = 0; m < 2; ++m)
#pragma unroll
                for (int n = 0; n < 4; ++n) acc[p][m][n] = zero;
        bf16x8 wa[2], wn[2];
        wa[0] = *reinterpret_cast<const bf16x8*>(wrow0);
        wa[1] = *reinterpret_cast<const bf16x8*>(wrow1);
#pragma unroll
        for (int k0 = 0; k0 < 8; ++k0) {
            if (k0 < 7) {
                wn[0] = *reinterpret_cast<const bf16x8*>(wrow0 + (k0 + 1) * 32);
                wn[1] = *reinterpret_cast<const bf16x8*>(wrow1 + (k0 + 1) * 32);
            }
            bf16x8 ba[4], bb[4];
#pragma unroll
            for (int n = 0; n < 4; ++n) {
                ba[n] = *reinterpret_cast<const bf16x8*>(xbase0 + n * (16 * LDX) + k0 * 32);
                bb[n] = *reinterpret_cast<const bf16x8*>(xbase1 + n * (16 * LDX) + k0 * 32);
            }
#pragma unroll
            for (int m = 0; m < 2; ++m)
#pragma unroll
                for (int n = 0; n < 4; ++n)
                    acc[0][m][n] =
                        __builtin_amdgcn_mfma_f32_16x16x32_bf16(wa[m], ba[n], acc[0][m][n], 0, 0, 0);
#pragma unroll
            for (int m = 0; m < 2; ++m)
#pragma unroll
                for (int n = 0; n < 4; ++n)
                    acc[1][m][n] =
                        __builtin_amdgcn_mfma_f32_16x16x32_bf16(wa[m], bb[n], acc[1][m][n], 0, 0, 0);
            wa[0] = wn[0];
            wa[1] = wn[1];
        }
    };

    __syncthreads();

    // ---- stage 1: y1^T = Wt1 . X^T ; X = bf16(swish2(y1)) ----
    run_gemm(Wt1);
    float4 pa[2], pb[2];
#pragma unroll
    for (int m = 0; m < 2; ++m) {  // param-load latency overlaps barrier wait
        pa[m] = *reinterpret_cast<const float4*>(a2g + f0 + m * 16);
        pb[m] = *reinterpret_cast<const float4*>(be2g + f0 + m * 16);
    }
    __syncthreads();
#pragma unroll
    for (int p = 0; p < 2; ++p)
#pragma unroll
        for (int m = 0; m < 2; ++m) {
            const int fm = f0 + m * 16;
#pragma unroll
            for (int n = 0; n < 4; ++n) {
                f32x4 y = acc[p][m][n];
                float s0 = pa[m].x * y[0] * fast_sigm(pb[m].x * y[0]);
                float s1 = pa[m].y * y[1] * fast_sigm(pb[m].y * y[1]);
                float s2 = pa[m].z * y[2] * fast_sigm(pb[m].z * y[2]);
                float s3 = pa[m].w * y[3] * fast_sigm(pb[m].w * y[3]);
                uint2 pk;
                pk.x = cvt_pk_bf16(s0, s1);
                pk.y = cvt_pk_bf16(s2, s3);
                *reinterpret_cast<uint2*>(&X[p][n * 16 + l15][fm]) = pk;
            }
        }
    __syncthreads();

    // ---- stage 2: y2^T = Wt2 . X^T ; h = av + y2 ; X = bf16(swish3(h)) ----
    run_gemm(Wt2);
    float4 pv0[2], pv1[2];
#pragma unroll
    for (int m = 0; m < 2; ++m) {
        pa[m] = *reinterpret_cast<const float4*>(a3g + f0 + m * 16);
        pb[m] = *reinterpret_cast<const float4*>(be3g + f0 + m * 16);
        pv0[m] = pos0 ? *reinterpret_cast<const float4*>(vp + f0 + m * 16)
                      : *reinterpret_cast<const float4*>(vm + f0 + m * 16);
        pv1[m] = pos1 ? *reinterpret_cast<const float4*>(vp + f0 + m * 16)
                      : *reinterpret_cast<const float4*>(vm + f0 + m * 16);
    }
    float aln0[4], aln1[4];
#pragma unroll
    for (int n = 0; n < 4; ++n) {
        aln0[n] = __shfl(aL0, n * 16 + l15, 64);
        aln1[n] = __shfl(aL1, n * 16 + l15, 64);
    }
    __syncthreads();
#pragma unroll
    for (int p = 0; p < 2; ++p)
#pragma unroll
        for (int m = 0; m < 2; ++m) {
            const int fm = f0 + m * 16;
            const float4 pv = p ? pv1[m] : pv0[m];
#pragma unroll
            for (int n = 0; n < 4; ++n) {
                const float al = p ? aln1[n] : aln0[n];
                f32x4 y = acc[p][m][n];
                float h0 = fmaf(al, pv.x, y[0]);
                float h1 = fmaf(al, pv.y, y[1]);
                float h2 = fmaf(al, pv.z, y[2]);
                float h3 = fmaf(al, pv.w, y[3]);
                float s0 = pa[m].x * h0 * fast_sigm(pb[m].x * h0);
                float s1 = pa[m].y * h1 * fast_sigm(pb[m].y * h1);
                float s2 = pa[m].z * h2 * fast_sigm(pb[m].z * h2);
                float s3 = pa[m].w * h3 * fast_sigm(pb[m].w * h3);
                uint2 pk;
                pk.x = cvt_pk_bf16(s0, s1);
                pk.y = cvt_pk_bf16(s2, s3);
                *reinterpret_cast<uint2*>(&X[p][n * 16 + l15][fm]) = pk;
            }
        }
    __syncthreads();

    // ---- stage 3: out^T = Wt3 . X^T + b_out ; n-outer/m-inner fills 128B lines ----
    run_gemm(Wt3);
    float4 bbv[2];
#pragma unroll
    for (int m = 0; m < 2; ++m)
        bbv[m] = *reinterpret_cast<const float4*>(b_out + f0 + m * 16);
#pragma unroll
    for (int p = 0; p < 2; ++p) {
        const int mol = p ? mol1 : mol0;
#pragma unroll
        for (int n = 0; n < 4; ++n) {
            float* orow = out + ((size_t)mol * NATOMS + n * 16 + l15) * FDIM + f0;
#pragma unroll
            for (int m = 0; m < 2; ++m) {
                float4 r;
                r.x = acc[p][m][n][0] + bbv[m].x;
                r.y = acc[p][m][n][1] + bbv[m].y;
                r.z = acc[p][m][n][2] + bbv[m].z;
                r.w = acc[p][m][n][3] + bbv[m].w;
                *reinterpret_cast<float4*>(orow + m * 16) = r;
            }
        }
    }
}

extern "C" void kernel_launch(void* const* d_in, const int* in_sizes, int n_in,
                              void* d_out, int out_size, void* d_ws, size_t ws_size,
                              hipStream_t stream) {
    const float* psi     = (const float*)d_in[0];
    const float* e_z     = (const float*)d_in[1];
    // d_in[2] = num_atoms (uniformly 64)
    const float* W_lin   = (const float*)d_in[3];
    const float* b_lin   = (const float*)d_in[4];
    const float* k_plus  = (const float*)d_in[5];
    const float* k_minus = (const float*)d_in[6];
    const float* v_plus  = (const float*)d_in[7];
    const float* v_minus = (const float*)d_in[8];
    const float* W_r1    = (const float*)d_in[9];
    const float* W_r2    = (const float*)d_in[10];
    const float* W_out   = (const float*)d_in[11];
    const float* b_out   = (const float*)d_in[12];
    const float* a1      = (const float*)d_in[13];
    const float* be1     = (const float*)d_in[14];
    const float* a2      = (const float*)d_in[15];
    const float* be2     = (const float*)d_in[16];
    const float* a3      = (const float*)d_in[17];
    const float* be3     = (const float*)d_in[18];
    float* out = (float*)d_out;

    char* ws = (char*)d_ws;
    float* wkp = (float*)ws;
    float* wkm = wkp + FDIM;
    float* bk2 = wkm + FDIM;
    __hip_bfloat16* Wt1 = (__hip_bfloat16*)(ws + 4096);
    __hip_bfloat16* Wt2 = Wt1 + FDIM * FDIM;
    __hip_bfloat16* Wt3 = Wt2 + FDIM * FDIM;

    const int n_mol = in_sizes[0];

    prep_wk<<<FDIM, FDIM, 0, stream>>>(W_lin, b_lin, k_plus, k_minus, wkp, wkm, bk2);
    prep_wt<<<3 * FDIM, FDIM, 0, stream>>>(W_r1, W_r2, W_out, Wt1, Wt2, Wt3);
    fused_ee<<<n_mol / 2, 512, 0, stream>>>(psi, e_z, wkp, wkm, bk2, v_plus, v_minus,
                                            Wt1, Wt2, Wt3, a1, be1, a2, be2, a3, be3,
                                            b_out, out);
}